// Round 1
// baseline (736.261 us; speedup 1.0000x reference)
//
#include <hip/hip_runtime.h>
#include <hip/hip_bf16.h>

#define CD 512
#define PD 4096
#define BD 16

typedef __bf16 bf16x8 __attribute__((ext_vector_type(8)));
typedef float f32x4 __attribute__((ext_vector_type(4)));
typedef unsigned short u16x8 __attribute__((ext_vector_type(8)));
typedef unsigned short u16x4 __attribute__((ext_vector_type(4)));

__device__ __forceinline__ unsigned short f2bf(float f) {
  unsigned u = __builtin_bit_cast(unsigned, f);
  u += 0x7FFFu + ((u >> 16) & 1u);   // RNE
  return (unsigned short)(u >> 16);
}
__device__ __forceinline__ float bf2f(unsigned short h) {
  unsigned u = ((unsigned)h) << 16;
  return __builtin_bit_cast(float, u);
}

// ---- W conversion: fp32 -> hi/lo bf16 (Wq, Wk split; Wv plain) ----
__global__ void convert_w(const float* __restrict__ Wq, const float* __restrict__ Wk,
                          const float* __restrict__ Wv,
                          unsigned short* __restrict__ Wq_hi, unsigned short* __restrict__ Wq_lo,
                          unsigned short* __restrict__ Wk_hi, unsigned short* __restrict__ Wk_lo,
                          unsigned short* __restrict__ Wv_hi) {
  int i = blockIdx.x * 256 + threadIdx.x;
  if (i >= CD * CD) return;
  float q = Wq[i]; unsigned short qh = f2bf(q);
  Wq_hi[i] = qh; Wq_lo[i] = f2bf(q - bf2f(qh));
  float k = Wk[i]; unsigned short kh = f2bf(k);
  Wk_hi[i] = kh; Wk_lo[i] = f2bf(k - bf2f(kh));
  Wv_hi[i] = f2bf(Wv[i]);
}

// ---- x[b][c][p] fp32 -> xT[b][p][c] hi/lo bf16 (tile transpose via LDS) ----
__global__ void transpose_split_x(const float* __restrict__ x,
                                  unsigned short* __restrict__ xThi,
                                  unsigned short* __restrict__ xTlo) {
  __shared__ float t[64][65];
  int z = blockIdx.z;
  const float* xb = x + (size_t)z * CD * PD;
  int p0 = blockIdx.x * 64, c0 = blockIdx.y * 64;
  int tid = threadIdx.x;
  int tr = tid >> 4, tc = tid & 15;
#pragma unroll
  for (int j = 0; j < 4; ++j) {
    int r = tr + j * 16;  // c-local
    const float* src = xb + (size_t)(c0 + r) * PD + p0 + tc * 4;
#pragma unroll
    for (int i = 0; i < 4; ++i) t[r][tc * 4 + i] = src[i];
  }
  __syncthreads();
  size_t ob = (size_t)z * PD * CD;
#pragma unroll
  for (int j = 0; j < 4; ++j) {
    int pr = tr + j * 16;  // p-local
    u16x4 hv, lv;
#pragma unroll
    for (int i = 0; i < 4; ++i) {
      float v = t[tc * 4 + i][pr];
      unsigned short h = f2bf(v);
      hv[i] = h;
      lv[i] = f2bf(v - bf2f(h));
    }
    size_t o = ob + (size_t)(p0 + pr) * CD + c0 + tc * 4;
    *reinterpret_cast<u16x4*>(xThi + o) = hv;
    *reinterpret_cast<u16x4*>(xTlo + o) = lv;
  }
}

// ---- generic C[M][N] = A[M][K] * B[N][K]^T, bf16 MFMA 16x16x32 ----
// SPLIT: A,B given as hi/lo pairs; acc += Ahi*Bhi + Ahi*Blo + Alo*Bhi.
enum { EPI_F32 = 0, EPI_QK = 1, EPI_V = 2 };

template <int BM, int BN, int WM, int WN, bool SPLIT, int EPI>
__global__ __launch_bounds__((BM / WM) * (BN / WN) * 64) void gemm_abt(
    const unsigned short* __restrict__ Ahi, const unsigned short* __restrict__ Alo,
    const unsigned short* __restrict__ Bhi, const unsigned short* __restrict__ Blo,
    long long sA, long long sB, int ldA, int ldB, int K,
    float* __restrict__ Cf, unsigned short* __restrict__ Chi, unsigned short* __restrict__ Clo,
    long long sC, int ldC, const float* __restrict__ bias) {
  constexpr int NWN = BN / WN;
  constexpr int MI = WM / 16, NI = WN / 16;
  constexpr int THREADS = (BM / WM) * (BN / WN) * 64;
  constexpr int NS = SPLIT ? 2 : 1;
  static_assert(THREADS == 256, "block must be 256");
  __shared__ unsigned short lsA[NS][BM][32];
  __shared__ unsigned short lsB[NS][BN][32];

  int z = blockIdx.z;
  const unsigned short* A0 = Ahi + (size_t)z * sA + (size_t)blockIdx.x * BM * ldA;
  const unsigned short* B0 = Bhi + (size_t)z * sB + (size_t)blockIdx.y * BN * ldB;
  const unsigned short* A1 = SPLIT ? (Alo + (size_t)z * sA + (size_t)blockIdx.x * BM * ldA) : A0;
  const unsigned short* B1 = SPLIT ? (Blo + (size_t)z * sB + (size_t)blockIdx.y * BN * ldB) : B0;

  int tid = threadIdx.x;
  int lane = tid & 63, wid = tid >> 6;
  int wr = wid / NWN, wc = wid % NWN;
  int lr = lane & 15, lk = (lane >> 4) * 8;

  f32x4 acc[MI][NI] = {};

  for (int k0 = 0; k0 < K; k0 += 32) {
#pragma unroll
    for (int ch = tid; ch < BM * 4; ch += THREADS) {
      int r = ch >> 2, o = (ch & 3) * 8;
      *reinterpret_cast<u16x8*>(&lsA[0][r][o]) =
          *reinterpret_cast<const u16x8*>(A0 + (size_t)r * ldA + k0 + o);
      if constexpr (SPLIT)
        *reinterpret_cast<u16x8*>(&lsA[1][r][o]) =
            *reinterpret_cast<const u16x8*>(A1 + (size_t)r * ldA + k0 + o);
    }
#pragma unroll
    for (int ch = tid; ch < BN * 4; ch += THREADS) {
      int r = ch >> 2, o = (ch & 3) * 8;
      *reinterpret_cast<u16x8*>(&lsB[0][r][o]) =
          *reinterpret_cast<const u16x8*>(B0 + (size_t)r * ldB + k0 + o);
      if constexpr (SPLIT)
        *reinterpret_cast<u16x8*>(&lsB[1][r][o]) =
            *reinterpret_cast<const u16x8*>(B1 + (size_t)r * ldB + k0 + o);
    }
    __syncthreads();

    bf16x8 ah[MI], al[MI], bh[NI], bl[NI];
#pragma unroll
    for (int m = 0; m < MI; ++m) {
      int row = wr * WM + m * 16 + lr;
      ah[m] = *reinterpret_cast<const bf16x8*>(&lsA[0][row][lk]);
      if constexpr (SPLIT) al[m] = *reinterpret_cast<const bf16x8*>(&lsA[1][row][lk]);
    }
#pragma unroll
    for (int n = 0; n < NI; ++n) {
      int col = wc * WN + n * 16 + lr;
      bh[n] = *reinterpret_cast<const bf16x8*>(&lsB[0][col][lk]);
      if constexpr (SPLIT) bl[n] = *reinterpret_cast<const bf16x8*>(&lsB[1][col][lk]);
    }
#pragma unroll
    for (int m = 0; m < MI; ++m)
#pragma unroll
      for (int n = 0; n < NI; ++n) {
        acc[m][n] = __builtin_amdgcn_mfma_f32_16x16x32_bf16(ah[m], bh[n], acc[m][n], 0, 0, 0);
        if constexpr (SPLIT) {
          acc[m][n] = __builtin_amdgcn_mfma_f32_16x16x32_bf16(ah[m], bl[n], acc[m][n], 0, 0, 0);
          acc[m][n] = __builtin_amdgcn_mfma_f32_16x16x32_bf16(al[m], bh[n], acc[m][n], 0, 0, 0);
        }
      }
    __syncthreads();
  }

  // epilogue: D layout col = lane&15, row = (lane>>4)*4 + reg (guide-verified)
  int lg = lane >> 4;
  int rb = blockIdx.x * BM + wr * WM;
  int cbase = blockIdx.y * BN + wc * WN;
#pragma unroll
  for (int m = 0; m < MI; ++m)
#pragma unroll
    for (int n = 0; n < NI; ++n) {
      int col = cbase + n * 16 + lr;
#pragma unroll
      for (int r = 0; r < 4; ++r) {
        int row = rb + m * 16 + lg * 4 + r;
        size_t idx = (size_t)z * sC + (size_t)row * ldC + col;
        float v = acc[m][n][r];
        if constexpr (EPI == EPI_F32) {
          Cf[idx] = v;
        } else if constexpr (EPI == EPI_QK) {
          v += bias[row];
          unsigned short h = f2bf(v);
          Chi[idx] = h;
          Clo[idx] = f2bf(v - bf2f(h));
        } else {  // EPI_V: bias indexed by output col (o-channel)
          v += bias[col];
          Chi[idx] = f2bf(v);
        }
      }
    }
}

// ---- row softmax: E fp32 [rows][512] -> attn bf16; one wave per row ----
__global__ void softmax_rows(const float* __restrict__ E, unsigned short* __restrict__ attn) {
  int lane = threadIdx.x & 63, wid = threadIdx.x >> 6;
  size_t row = (size_t)blockIdx.x * 4 + wid;
  const float* e = E + row * CD;
  const float4* ep = reinterpret_cast<const float4*>(e + lane * 8);
  float4 a = ep[0], b = ep[1];
  float v[8] = {a.x, a.y, a.z, a.w, b.x, b.y, b.z, b.w};
  float m = v[0];
#pragma unroll
  for (int i = 1; i < 8; ++i) m = fmaxf(m, v[i]);
  for (int o = 32; o > 0; o >>= 1) m = fmaxf(m, __shfl_xor(m, o));
  float s = 0.f;
#pragma unroll
  for (int i = 0; i < 8; ++i) { v[i] = __expf(v[i] - m); s += v[i]; }
  for (int o = 32; o > 0; o >>= 1) s += __shfl_xor(s, o);
  float rinv = 1.0f / s;
  u16x4 h0, h1;
#pragma unroll
  for (int i = 0; i < 4; ++i) { h0[i] = f2bf(v[i] * rinv); h1[i] = f2bf(v[4 + i] * rinv); }
  unsigned short* op = attn + row * CD + lane * 8;
  *reinterpret_cast<u16x4*>(op) = h0;
  *reinterpret_cast<u16x4*>(op + 4) = h1;
}

extern "C" void kernel_launch(void* const* d_in, const int* in_sizes, int n_in,
                              void* d_out, int out_size, void* d_ws, size_t ws_size,
                              hipStream_t stream) {
  (void)in_sizes; (void)n_in; (void)out_size;
  const float* x  = (const float*)d_in[0];
  const float* Wq = (const float*)d_in[1];
  const float* bq = (const float*)d_in[2];
  const float* Wk = (const float*)d_in[3];
  const float* bk = (const float*)d_in[4];
  const float* Wv = (const float*)d_in[5];
  const float* bv = (const float*)d_in[6];
  float* out = (float*)d_out;

  char* base = (char*)d_ws;
  size_t off = 0;
  auto carve = [&](size_t bytes) -> char* {
    char* p = base + off;
    off += (bytes + 255) & ~(size_t)255;
    return p;
  };
  const size_t WB = (size_t)CD * CD * 2;
  unsigned short* Wq_hi = (unsigned short*)carve(WB);
  unsigned short* Wq_lo = (unsigned short*)carve(WB);
  unsigned short* Wk_hi = (unsigned short*)carve(WB);
  unsigned short* Wk_lo = (unsigned short*)carve(WB);
  unsigned short* Wv_hi = (unsigned short*)carve(WB);

  const size_t CP = (size_t)CD * PD;  // elems per batch plane
  const size_t per_batch = 7 * (CP * 2) + (size_t)CD * CD * 4 + (size_t)CD * CD * 2 + 16 * 256;
  size_t rem = (ws_size > off + 4096) ? (ws_size - off - 4096) : 0;
  int nb = (int)(rem / per_batch);
  if (nb < 1) nb = 1;
  if (nb > BD) nb = BD;

  unsigned short* xThi = (unsigned short*)carve((size_t)nb * CP * 2);
  unsigned short* xTlo = (unsigned short*)carve((size_t)nb * CP * 2);
  unsigned short* q_hi = (unsigned short*)carve((size_t)nb * CP * 2);
  unsigned short* q_lo = (unsigned short*)carve((size_t)nb * CP * 2);
  unsigned short* k_hi = (unsigned short*)carve((size_t)nb * CP * 2);
  unsigned short* k_lo = (unsigned short*)carve((size_t)nb * CP * 2);
  unsigned short* vT   = (unsigned short*)carve((size_t)nb * CP * 2);
  float*          E    = (float*)carve((size_t)nb * CD * CD * 4);
  unsigned short* attn = (unsigned short*)carve((size_t)nb * CD * CD * 2);

  convert_w<<<dim3((CD * CD + 255) / 256), 256, 0, stream>>>(
      Wq, Wk, Wv, Wq_hi, Wq_lo, Wk_hi, Wk_lo, Wv_hi);

  for (int b0 = 0; b0 < BD; b0 += nb) {
    int cb = (BD - b0 < nb) ? (BD - b0) : nb;

    transpose_split_x<<<dim3(PD / 64, CD / 64, cb), 256, 0, stream>>>(
        x + (size_t)b0 * CP, xThi, xTlo);

    // Q = Wq*X + bq  (M=o, N=p, K=i), split path, writes q hi/lo [c][p]
    gemm_abt<128, 128, 64, 64, true, EPI_QK><<<dim3(CD / 128, PD / 128, cb), 256, 0, stream>>>(
        Wq_hi, Wq_lo, xThi, xTlo, 0, (long long)CP, CD, CD, CD,
        nullptr, q_hi, q_lo, (long long)CP, PD, bq);
    // K = Wk*X + bk
    gemm_abt<128, 128, 64, 64, true, EPI_QK><<<dim3(CD / 128, PD / 128, cb), 256, 0, stream>>>(
        Wk_hi, Wk_lo, xThi, xTlo, 0, (long long)CP, CD, CD, CD,
        nullptr, k_hi, k_lo, (long long)CP, PD, bk);
    // vT[p][o] = sum_i xT[p][i] Wv[o][i] + bv[o]  (M=p, N=o, K=i), plain bf16
    gemm_abt<128, 128, 64, 64, false, EPI_V><<<dim3(PD / 128, CD / 128, cb), 256, 0, stream>>>(
        xThi, nullptr, Wv_hi, nullptr, (long long)CP, 0, CD, CD, CD,
        nullptr, vT, nullptr, (long long)CP, CD, bv);
    // E = Q K^T  (M=c, N=d, K=p), split path, fp32 out
    gemm_abt<128, 64, 64, 32, true, EPI_F32><<<dim3(CD / 128, CD / 64, cb), 256, 0, stream>>>(
        q_hi, q_lo, k_hi, k_lo, (long long)CP, (long long)CP, PD, PD, PD,
        E, nullptr, nullptr, (long long)CD * CD, CD, nullptr);

    softmax_rows<<<dim3(cb * CD / 4), 256, 0, stream>>>(E, attn);

    // out = attn * V  (M=c, N=p, K=d), B = vT[p][d]
    gemm_abt<128, 128, 64, 64, false, EPI_F32><<<dim3(CD / 128, PD / 128, cb), 256, 0, stream>>>(
        attn, nullptr, vT, nullptr, (long long)CD * CD, (long long)CP, CD, CD, CD,
        out + (size_t)b0 * CP, nullptr, nullptr, (long long)CP, PD, nullptr);
  }
}

// Round 2
// 392.230 us; speedup vs baseline: 1.8771x; 1.8771x over previous
//
#include <hip/hip_runtime.h>
#include <hip/hip_bf16.h>

#define CD 512
#define PD 4096
#define BD 16
#define CAUG 640   // padded augmented channel dim (544 -> 5*128)
#define KW 576     // padded K for W-side gemms (544 -> 9*64)

typedef __bf16 bf16x8 __attribute__((ext_vector_type(8)));
typedef float f32x4 __attribute__((ext_vector_type(4)));
typedef unsigned short u16x8 __attribute__((ext_vector_type(8)));
typedef unsigned short u16x4 __attribute__((ext_vector_type(4)));

__device__ __forceinline__ unsigned short f2bf(float f) {
  unsigned u = __builtin_bit_cast(unsigned, f);
  u += 0x7FFFu + ((u >> 16) & 1u);  // RNE
  return (unsigned short)(u >> 16);
}
__device__ __forceinline__ float bf2f(unsigned short h) {
  unsigned u = ((unsigned)h) << 16;
  return __builtin_bit_cast(float, u);
}

// ---- W~ = [W | b | 0pad] -> hi/lo bf16 [512][576]; Wv plain [512][512] ----
__global__ void convert_w2(const float* __restrict__ Wq, const float* __restrict__ bq,
                           const float* __restrict__ Wk, const float* __restrict__ bk,
                           const float* __restrict__ Wv,
                           unsigned short* __restrict__ Wqh, unsigned short* __restrict__ Wql,
                           unsigned short* __restrict__ Wkh, unsigned short* __restrict__ Wkl,
                           unsigned short* __restrict__ Wvh) {
  int i = blockIdx.x * 256 + threadIdx.x;
  if (i >= CD * KW) return;
  int o = i / KW, j = i - o * KW;
  float q = j < CD ? Wq[o * CD + j] : (j == CD ? bq[o] : 0.f);
  float k = j < CD ? Wk[o * CD + j] : (j == CD ? bk[o] : 0.f);
  unsigned short qh = f2bf(q), kh = f2bf(k);
  Wqh[i] = qh; Wql[i] = f2bf(q - bf2f(qh));
  Wkh[i] = kh; Wkl[i] = f2bf(k - bf2f(kh));
  if (j < CD) Wvh[o * CD + j] = f2bf(Wv[o * CD + j]);
}

// ---- x[b][512][4096] fp32 -> xs hi/lo [b][640][4096] (row512=1, rest pad=0)
//      + xThi [b][4096][512] bf16 (transposed, for V path) ----
__global__ void convert_x(const float* __restrict__ x, unsigned short* __restrict__ xsh,
                          unsigned short* __restrict__ xsl, unsigned short* __restrict__ xth) {
  int z = blockIdx.z, cy = blockIdx.y;
  int p0 = blockIdx.x * 64;
  int t = threadIdx.x;
  if (cy >= 8) {  // pad rows 512..639: row 512 = ones, rest zeros
    int row = 512 + (cy - 8) * 64 + (t >> 2);
    int cg = (t & 3) * 16;
    u16x8 h = (u16x8)0, l = (u16x8)0;
    if (row == 512)
#pragma unroll
      for (int i = 0; i < 8; ++i) h[i] = 0x3F80;  // 1.0 bf16
    size_t o = (size_t)z * CAUG * PD + (size_t)row * PD + p0 + cg;
    *reinterpret_cast<u16x8*>(xsh + o) = h;
    *reinterpret_cast<u16x8*>(xsh + o + 8) = h;
    *reinterpret_cast<u16x8*>(xsl + o) = l;
    *reinterpret_cast<u16x8*>(xsl + o + 8) = l;
    return;
  }
  __shared__ float tile[64][65];
  int c0 = cy * 64;
  const float* xb = x + (size_t)z * CD * PD;
  int tr = t >> 4, tc = t & 15;
#pragma unroll
  for (int j = 0; j < 4; ++j) {
    int r = tr + j * 16;
    const float* src = xb + (size_t)(c0 + r) * PD + p0 + tc * 4;
#pragma unroll
    for (int i = 0; i < 4; ++i) tile[r][tc * 4 + i] = src[i];
  }
  __syncthreads();
  // straight split write
#pragma unroll
  for (int j = 0; j < 4; ++j) {
    int r = tr + j * 16;
    u16x4 hv, lv;
#pragma unroll
    for (int i = 0; i < 4; ++i) {
      float v = tile[r][tc * 4 + i];
      unsigned short h = f2bf(v);
      hv[i] = h; lv[i] = f2bf(v - bf2f(h));
    }
    size_t o = (size_t)z * CAUG * PD + (size_t)(c0 + r) * PD + p0 + tc * 4;
    *reinterpret_cast<u16x4*>(xsh + o) = hv;
    *reinterpret_cast<u16x4*>(xsl + o) = lv;
  }
  // transposed hi write
#pragma unroll
  for (int j = 0; j < 4; ++j) {
    int pr = tr + j * 16;
    u16x4 hv;
#pragma unroll
    for (int i = 0; i < 4; ++i) hv[i] = f2bf(tile[tc * 4 + i][pr]);
    size_t o = (size_t)z * PD * CD + (size_t)(p0 + pr) * CD + c0 + tc * 4;
    *reinterpret_cast<u16x4*>(xth + o) = hv;
  }
}

// ---- generic C[M][N] = sum_k A[M][k]*B[N][k], bf16 MFMA 16x16x32, BK=64,
//      global_load_lds staging with XOR slot swizzle, 1D XCD-chunked grid ----
enum { EPI_F32 = 0, EPI_HILO = 1, EPI_V = 2 };

template <int BM, int BN, int WM, int WN, bool SPLIT, int EPI, bool TRI>
__global__ __launch_bounds__((BM / WM) * (BN / WN) * 64) void gemm2(
    const unsigned short* __restrict__ Ahi, const unsigned short* __restrict__ Alo,
    const unsigned short* __restrict__ Bhi, const unsigned short* __restrict__ Blo,
    long long sA, long long sB, int ldA, int ldB, int K,
    float* __restrict__ Cf, unsigned short* __restrict__ Chi, unsigned short* __restrict__ Clo,
    long long sC, int ldC, const float* __restrict__ bias, int gx, int gy) {
  constexpr int BK = 64;
  constexpr int WAVES = (BM / WM) * (BN / WN);
  constexpr int NS = SPLIT ? 2 : 1;
  constexpr int MI = WM / 16, NI = WN / 16;
  constexpr int NWN = BN / WN;
  constexpr int CA = BM / 8, CB = BN / 8;       // 1KB chunks per plane
  constexpr int TOT = NS * (CA + CB);
  __shared__ unsigned short lds[NS * (BM + BN) * BK];

  // bijective XCD-chunk swizzle (m204)
  int nwg = gridDim.x;
  int b = blockIdx.x;
  int q = nwg >> 3, r = nwg & 7, xcd = b & 7, pos = b >> 3;
  int wg = (xcd < r ? xcd * (q + 1) : r * (q + 1) + (xcd - r) * q) + pos;
  int bx, by, z;
  if constexpr (TRI) {
    int tri = gy * (gy + 1) / 2;
    z = wg / tri;
    int tp = wg - z * tri;
    bx = 0;
    while (tp >= gy - bx) { tp -= gy - bx; ++bx; }
    by = bx + tp;
  } else {
    by = wg % gy;
    int t2 = wg / gy;
    bx = t2 % gx;
    z = t2 / gx;
  }

  const unsigned short* pA0 = Ahi + (size_t)z * sA + (size_t)bx * BM * ldA;
  const unsigned short* pB0 = Bhi + (size_t)z * sB + (size_t)by * BN * ldB;
  const unsigned short* pA1 = SPLIT ? Alo + (size_t)z * sA + (size_t)bx * BM * ldA : pA0;
  const unsigned short* pB1 = SPLIT ? Blo + (size_t)z * sB + (size_t)by * BN * ldB : pB0;

  int tid = threadIdx.x;
  int lane = tid & 63, wid = tid >> 6;
  int wr = wid / NWN, wc = wid % NWN;
  int lr = lane & 15, kh2 = lane >> 4;

  f32x4 acc[MI][NI] = {};

  for (int k0 = 0; k0 < K; k0 += BK) {
    // stage: 8 rows x 64 elems per 1KB chunk; lane l -> row +(l>>3), phys slot l&7.
    // element for phys slot s at row r is logical slot s^(r&7)  (read applies same XOR)
#pragma unroll
    for (int i = 0; i < TOT / WAVES; ++i) {
      int c = wid + i * WAVES;
      const unsigned short* srcb; int ldX, lofs, rb2;
      if (c < CA)            { srcb = pA0; ldX = ldA; lofs = c * 512;                       rb2 = c * 8; }
      else if (c < NS * CA)  { srcb = pA1; ldX = ldA; lofs = BM * BK + (c - CA) * 512;      rb2 = (c - CA) * 8; }
      else if (c < NS * CA + CB) { int cc = c - NS * CA; srcb = pB0; ldX = ldB;
                                   lofs = NS * BM * BK + cc * 512;                          rb2 = cc * 8; }
      else                   { int cc = c - NS * CA - CB; srcb = pB1; ldX = ldB;
                               lofs = NS * BM * BK + BN * BK + cc * 512;                    rb2 = cc * 8; }
      int row = rb2 + (lane >> 3);
      const unsigned short* src =
          srcb + (size_t)row * ldX + k0 + (((lane & 7) ^ (row & 7)) << 3);
      __builtin_amdgcn_global_load_lds(
          (const __attribute__((address_space(1))) void*)src,
          (__attribute__((address_space(3))) void*)(lds + lofs), 16, 0, 0);
    }
    __syncthreads();

#pragma unroll
    for (int kk = 0; kk < BK / 32; ++kk) {
      bf16x8 ah[MI], al[MI], bh[NI], bl[NI];
#pragma unroll
      for (int m = 0; m < MI; ++m) {
        int row = wr * WM + m * 16 + lr;
        int so = ((((kk << 2) | kh2) ^ (row & 7)) << 3);
        ah[m] = *reinterpret_cast<const bf16x8*>(&lds[row * BK + so]);
        if constexpr (SPLIT)
          al[m] = *reinterpret_cast<const bf16x8*>(&lds[BM * BK + row * BK + so]);
      }
#pragma unroll
      for (int n = 0; n < NI; ++n) {
        int row = wc * WN + n * 16 + lr;
        int so = ((((kk << 2) | kh2) ^ (row & 7)) << 3);
        bh[n] = *reinterpret_cast<const bf16x8*>(&lds[NS * BM * BK + row * BK + so]);
        if constexpr (SPLIT)
          bl[n] = *reinterpret_cast<const bf16x8*>(&lds[NS * BM * BK + BN * BK + row * BK + so]);
      }
#pragma unroll
      for (int m = 0; m < MI; ++m)
#pragma unroll
        for (int n = 0; n < NI; ++n) {
          acc[m][n] = __builtin_amdgcn_mfma_f32_16x16x32_bf16(ah[m], bh[n], acc[m][n], 0, 0, 0);
          if constexpr (SPLIT) {
            acc[m][n] = __builtin_amdgcn_mfma_f32_16x16x32_bf16(ah[m], bl[n], acc[m][n], 0, 0, 0);
            acc[m][n] = __builtin_amdgcn_mfma_f32_16x16x32_bf16(al[m], bh[n], acc[m][n], 0, 0, 0);
          }
        }
    }
    __syncthreads();
  }

  // epilogue: C/D layout col = lane&15, row = (lane>>4)*4 + reg
  int lg = lane >> 4;
  int rb = bx * BM + wr * WM;
  int cbase = by * BN + wc * WN;
#pragma unroll
  for (int m = 0; m < MI; ++m)
#pragma unroll
    for (int n = 0; n < NI; ++n) {
      int col = cbase + n * 16 + lr;
      float bcol = (EPI == EPI_V) ? bias[col] : 0.f;
#pragma unroll
      for (int r4 = 0; r4 < 4; ++r4) {
        int row = rb + m * 16 + lg * 4 + r4;
        size_t idx = (size_t)z * sC + (size_t)row * ldC + col;
        float v = acc[m][n][r4];
        if constexpr (EPI == EPI_F32) {
          Cf[idx] = v;
        } else if constexpr (EPI == EPI_HILO) {
          unsigned short h = f2bf(v);
          Chi[idx] = h;
          Clo[idx] = f2bf(v - bf2f(h));
        } else {
          Chi[idx] = f2bf(v + bcol);
        }
      }
    }
}

// ---- mirror lower triangle of G~ from computed upper (128-block pairs bx<by) ----
__global__ void mirror_g(unsigned short* __restrict__ Ghi, unsigned short* __restrict__ Glo) {
  __shared__ unsigned short shh[64][72], shl[64][72];
  int z = blockIdx.y;
  int pidx = blockIdx.x >> 2, sub = blockIdx.x & 3;
  int bx = 0, tp = pidx;
  while (tp >= 4 - bx) { tp -= 4 - bx; ++bx; }
  int by = bx + 1 + tp;
  int ti = bx * 2 + (sub & 1), tj = by * 2 + (sub >> 1);
  int t = threadIdx.x;
  int rr = t >> 2, cg = (t & 3) * 16;
  size_t gbase = (size_t)z * CAUG * CAUG;
  size_t so = gbase + (size_t)(ti * 64 + rr) * CAUG + tj * 64 + cg;
  *reinterpret_cast<u16x8*>(&shh[rr][cg]) = *reinterpret_cast<const u16x8*>(Ghi + so);
  *reinterpret_cast<u16x8*>(&shh[rr][cg + 8]) = *reinterpret_cast<const u16x8*>(Ghi + so + 8);
  *reinterpret_cast<u16x8*>(&shl[rr][cg]) = *reinterpret_cast<const u16x8*>(Glo + so);
  *reinterpret_cast<u16x8*>(&shl[rr][cg + 8]) = *reinterpret_cast<const u16x8*>(Glo + so + 8);
  __syncthreads();
  u16x8 oh, ol;
  size_t dst = gbase + (size_t)(tj * 64 + rr) * CAUG + ti * 64 + cg;
#pragma unroll
  for (int half = 0; half < 2; ++half) {
#pragma unroll
    for (int i = 0; i < 8; ++i) {
      oh[i] = shh[cg + half * 8 + i][rr];
      ol[i] = shl[cg + half * 8 + i][rr];
    }
    *reinterpret_cast<u16x8*>(Ghi + dst + half * 8) = oh;
    *reinterpret_cast<u16x8*>(Glo + dst + half * 8) = ol;
  }
}

// ---- row softmax: E fp32 [rows][512] -> attn bf16; one wave per row ----
__global__ void softmax_rows(const float* __restrict__ E, unsigned short* __restrict__ attn) {
  int lane = threadIdx.x & 63, wid = threadIdx.x >> 6;
  size_t row = (size_t)blockIdx.x * 4 + wid;
  const float* e = E + row * CD;
  const float4* ep = reinterpret_cast<const float4*>(e + lane * 8);
  float4 a = ep[0], bq4 = ep[1];
  float v[8] = {a.x, a.y, a.z, a.w, bq4.x, bq4.y, bq4.z, bq4.w};
  float m = v[0];
#pragma unroll
  for (int i = 1; i < 8; ++i) m = fmaxf(m, v[i]);
  for (int o = 32; o > 0; o >>= 1) m = fmaxf(m, __shfl_xor(m, o));
  float s = 0.f;
#pragma unroll
  for (int i = 0; i < 8; ++i) { v[i] = __expf(v[i] - m); s += v[i]; }
  for (int o = 32; o > 0; o >>= 1) s += __shfl_xor(s, o);
  float rinv = 1.0f / s;
  u16x4 h0, h1;
#pragma unroll
  for (int i = 0; i < 4; ++i) { h0[i] = f2bf(v[i] * rinv); h1[i] = f2bf(v[4 + i] * rinv); }
  unsigned short* op = attn + row * CD + lane * 8;
  *reinterpret_cast<u16x4*>(op) = h0;
  *reinterpret_cast<u16x4*>(op + 4) = h1;
}

extern "C" void kernel_launch(void* const* d_in, const int* in_sizes, int n_in,
                              void* d_out, int out_size, void* d_ws, size_t ws_size,
                              hipStream_t stream) {
  (void)in_sizes; (void)n_in; (void)out_size;
  const float* x  = (const float*)d_in[0];
  const float* Wq = (const float*)d_in[1];
  const float* bq = (const float*)d_in[2];
  const float* Wk = (const float*)d_in[3];
  const float* bk = (const float*)d_in[4];
  const float* Wv = (const float*)d_in[5];
  const float* bv = (const float*)d_in[6];
  float* out = (float*)d_out;

  char* base = (char*)d_ws;
  size_t off = 0;
  auto carve = [&](size_t bytes) -> char* {
    char* p = base + off;
    off += (bytes + 255) & ~(size_t)255;
    return p;
  };
  unsigned short* Wqh = (unsigned short*)carve((size_t)CD * KW * 2);
  unsigned short* Wql = (unsigned short*)carve((size_t)CD * KW * 2);
  unsigned short* Wkh = (unsigned short*)carve((size_t)CD * KW * 2);
  unsigned short* Wkl = (unsigned short*)carve((size_t)CD * KW * 2);
  unsigned short* Wvh = (unsigned short*)carve((size_t)CD * CD * 2);

  const size_t CP = (size_t)CD * PD;
  const size_t XS = (size_t)CAUG * PD;
  const size_t XT = (size_t)PD * CD;
  const size_t GG = (size_t)CAUG * CAUG;
  const size_t TT = (size_t)CD * CAUG;
  const size_t EE = (size_t)CD * CD;
  const size_t per_batch = 2 * XS * 2 + XT * 2 + 2 * GG * 2 + 2 * TT * 2 + EE * 4 + EE * 2 + XT * 2 + 2048;
  size_t rem = (ws_size > off + 4096) ? (ws_size - off - 4096) : 0;
  int nb = (int)(rem / per_batch);
  if (nb < 1) nb = 1;
  if (nb > BD) nb = BD;

  unsigned short* xsh = (unsigned short*)carve((size_t)nb * XS * 2);
  unsigned short* xsl = (unsigned short*)carve((size_t)nb * XS * 2);
  unsigned short* xth = (unsigned short*)carve((size_t)nb * XT * 2);
  unsigned short* Ghi = (unsigned short*)carve((size_t)nb * GG * 2);
  unsigned short* Glo = (unsigned short*)carve((size_t)nb * GG * 2);
  unsigned short* Thi = (unsigned short*)carve((size_t)nb * TT * 2);
  unsigned short* Tlo = (unsigned short*)carve((size_t)nb * TT * 2);
  float*          E   = (float*)carve((size_t)nb * EE * 4);
  unsigned short* att = (unsigned short*)carve((size_t)nb * EE * 2);
  unsigned short* vT  = (unsigned short*)carve((size_t)nb * XT * 2);

  convert_w2<<<dim3((CD * KW + 255) / 256), 256, 0, stream>>>(
      Wq, bq, Wk, bk, Wv, Wqh, Wql, Wkh, Wkl, Wvh);

  for (int b0 = 0; b0 < BD; b0 += nb) {
    int cb = (BD - b0 < nb) ? (BD - b0) : nb;

    convert_x<<<dim3(PD / 64, 10, cb), 256, 0, stream>>>(x + (size_t)b0 * CP, xsh, xsl, xth);

    // G~ = Xa Xa^T (upper triangle blocks), split 3-term, hi/lo out
    gemm2<128, 128, 64, 32, true, EPI_HILO, true><<<15 * cb, 512, 0, stream>>>(
        xsh, xsl, xsh, xsl, (long long)XS, (long long)XS, PD, PD, PD,
        nullptr, Ghi, Glo, (long long)GG, CAUG, nullptr, 5, 5);

    mirror_g<<<dim3(40, cb), 256, 0, stream>>>(Ghi, Glo);

    // T = Wq~ * G~^T  (G symmetric), split, hi/lo out  [512][640]
    gemm2<64, 64, 32, 32, true, EPI_HILO, false><<<8 * 10 * cb, 256, 0, stream>>>(
        Wqh, Wql, Ghi, Glo, 0, (long long)GG, KW, CAUG, KW,
        nullptr, Thi, Tlo, (long long)TT, CAUG, nullptr, 8, 10);

    // E = T * Wk~^T, split, fp32 out [512][512]
    gemm2<64, 64, 32, 32, true, EPI_F32, false><<<8 * 8 * cb, 256, 0, stream>>>(
        Thi, Tlo, Wkh, Wkl, (long long)TT, 0, CAUG, KW, KW,
        E, nullptr, nullptr, (long long)EE, CD, nullptr, 8, 8);

    softmax_rows<<<dim3(cb * CD / 4), 256, 0, stream>>>(E, att);

    // vT[p][o] = xT * Wv^T + bv  [4096][512]
    gemm2<128, 128, 64, 64, false, EPI_V, false><<<32 * 4 * cb, 256, 0, stream>>>(
        xth, nullptr, Wvh, nullptr, (long long)XT, 0, CD, CD, CD,
        nullptr, vT, nullptr, (long long)XT, CD, bv, 32, 4);

    // out = attn * vT^T  [512][4096] fp32
    gemm2<128, 128, 64, 64, false, EPI_F32, false><<<4 * 32 * cb, 256, 0, stream>>>(
        att, nullptr, vT, nullptr, (long long)EE, (long long)XT, CD, CD, CD,
        out + (size_t)b0 * CP, nullptr, nullptr, (long long)CP, PD, nullptr, 4, 32);
  }
}

// Round 3
// 352.572 us; speedup vs baseline: 2.0883x; 1.1125x over previous
//
#include <hip/hip_runtime.h>
#include <hip/hip_bf16.h>

#define CD 512
#define PD 4096
#define BD 16
#define CAUG 640   // padded augmented channel dim (544 -> 5*128)
#define KW 576     // padded K for W-side gemms (544 -> 9*64)
#define GKS 4      // Gram split-K factor (K chunks of 1024)

typedef __bf16 bf16x8 __attribute__((ext_vector_type(8)));
typedef float f32x4 __attribute__((ext_vector_type(4)));
typedef unsigned short u16x8 __attribute__((ext_vector_type(8)));
typedef unsigned short u16x4 __attribute__((ext_vector_type(4)));

__device__ __forceinline__ unsigned short f2bf(float f) {
  unsigned u = __builtin_bit_cast(unsigned, f);
  u += 0x7FFFu + ((u >> 16) & 1u);  // RNE
  return (unsigned short)(u >> 16);
}
__device__ __forceinline__ float bf2f(unsigned short h) {
  unsigned u = ((unsigned)h) << 16;
  return __builtin_bit_cast(float, u);
}

// ---- W~ = [W | b | 0pad] -> hi/lo bf16 [512][576]; Wv plain [512][512] ----
__global__ void convert_w2(const float* __restrict__ Wq, const float* __restrict__ bq,
                           const float* __restrict__ Wk, const float* __restrict__ bk,
                           const float* __restrict__ Wv,
                           unsigned short* __restrict__ Wqh, unsigned short* __restrict__ Wql,
                           unsigned short* __restrict__ Wkh, unsigned short* __restrict__ Wkl,
                           unsigned short* __restrict__ Wvh) {
  int i = blockIdx.x * 256 + threadIdx.x;
  if (i >= CD * KW) return;
  int o = i / KW, j = i - o * KW;
  float q = j < CD ? Wq[o * CD + j] : (j == CD ? bq[o] : 0.f);
  float k = j < CD ? Wk[o * CD + j] : (j == CD ? bk[o] : 0.f);
  unsigned short qh = f2bf(q), kh = f2bf(k);
  Wqh[i] = qh; Wql[i] = f2bf(q - bf2f(qh));
  Wkh[i] = kh; Wkl[i] = f2bf(k - bf2f(kh));
  if (j < CD) Wvh[o * CD + j] = f2bf(Wv[o * CD + j]);
}

// ---- x[b][512][4096] fp32 -> xs hi/lo [b][640][4096] (row512=1, rest pad=0)
//      + xThi [b][4096][512] bf16 (transposed, for V path) ----
__global__ void convert_x(const float* __restrict__ x, unsigned short* __restrict__ xsh,
                          unsigned short* __restrict__ xsl, unsigned short* __restrict__ xth) {
  int z = blockIdx.z, cy = blockIdx.y;
  int p0 = blockIdx.x * 64;
  int t = threadIdx.x;
  if (cy >= 8) {  // pad rows 512..639: row 512 = ones, rest zeros
    int row = 512 + (cy - 8) * 64 + (t >> 2);
    int cg = (t & 3) * 16;
    u16x8 h = (u16x8)0, l = (u16x8)0;
    if (row == 512)
#pragma unroll
      for (int i = 0; i < 8; ++i) h[i] = 0x3F80;  // 1.0 bf16
    size_t o = (size_t)z * CAUG * PD + (size_t)row * PD + p0 + cg;
    *reinterpret_cast<u16x8*>(xsh + o) = h;
    *reinterpret_cast<u16x8*>(xsh + o + 8) = h;
    *reinterpret_cast<u16x8*>(xsl + o) = l;
    *reinterpret_cast<u16x8*>(xsl + o + 8) = l;
    return;
  }
  __shared__ float tile[64][65];
  int c0 = cy * 64;
  const float* xb = x + (size_t)z * CD * PD;
  int tr = t >> 4, tc = t & 15;
#pragma unroll
  for (int j = 0; j < 4; ++j) {
    int r = tr + j * 16;
    const float* src = xb + (size_t)(c0 + r) * PD + p0 + tc * 4;
#pragma unroll
    for (int i = 0; i < 4; ++i) tile[r][tc * 4 + i] = src[i];
  }
  __syncthreads();
  // straight split write
#pragma unroll
  for (int j = 0; j < 4; ++j) {
    int r = tr + j * 16;
    u16x4 hv, lv;
#pragma unroll
    for (int i = 0; i < 4; ++i) {
      float v = tile[r][tc * 4 + i];
      unsigned short h = f2bf(v);
      hv[i] = h; lv[i] = f2bf(v - bf2f(h));
    }
    size_t o = (size_t)z * CAUG * PD + (size_t)(c0 + r) * PD + p0 + tc * 4;
    *reinterpret_cast<u16x4*>(xsh + o) = hv;
    *reinterpret_cast<u16x4*>(xsl + o) = lv;
  }
  // transposed hi write
#pragma unroll
  for (int j = 0; j < 4; ++j) {
    int pr = tr + j * 16;
    u16x4 hv;
#pragma unroll
    for (int i = 0; i < 4; ++i) hv[i] = f2bf(tile[tc * 4 + i][pr]);
    size_t o = (size_t)z * PD * CD + (size_t)(p0 + pr) * CD + c0 + tc * 4;
    *reinterpret_cast<u16x4*>(xth + o) = hv;
  }
}

// ---- generic C[M][N] = sum_k A[M][k]*B[N][k], bf16 MFMA 16x16x32, BK=64,
//      global_load_lds staging with XOR slot swizzle, 1D XCD-chunked grid.
//      TRI: upper-triangle block grid (Gram). SPLITK>1 (TRI only): K arg is the
//      chunk length; compact fp32 partial output [zc][tri][BM][BN]. ----
enum { EPI_F32 = 0, EPI_HILO = 1, EPI_V = 2 };

template <int BM, int BN, int WM, int WN, bool SPLIT, int EPI, bool TRI, int SPLITK = 1>
__global__ __launch_bounds__((BM / WM) * (BN / WN) * 64) void gemm2(
    const unsigned short* __restrict__ Ahi, const unsigned short* __restrict__ Alo,
    const unsigned short* __restrict__ Bhi, const unsigned short* __restrict__ Blo,
    long long sA, long long sB, int ldA, int ldB, int K,
    float* __restrict__ Cf, unsigned short* __restrict__ Chi, unsigned short* __restrict__ Clo,
    long long sC, int ldC, const float* __restrict__ bias, int gx, int gy) {
  constexpr int BK = 64;
  constexpr int WAVES = (BM / WM) * (BN / WN);
  constexpr int NS = SPLIT ? 2 : 1;
  constexpr int MI = WM / 16, NI = WN / 16;
  constexpr int NWN = BN / WN;
  constexpr int CA = BM / 8, CB = BN / 8;  // 1KB chunks per plane
  constexpr int TOT = NS * (CA + CB);
  constexpr bool COMPACT = TRI && (SPLITK > 1);
  __shared__ unsigned short lds[NS * (BM + BN) * BK];

  // bijective XCD-chunk swizzle (m204)
  int nwg = gridDim.x;
  int b = blockIdx.x;
  int q = nwg >> 3, r = nwg & 7, xcd = b & 7, pos = b >> 3;
  int wg = (xcd < r ? xcd * (q + 1) : r * (q + 1) + (xcd - r) * q) + pos;
  int bx, by, z, zc, tpi = 0, kbase = 0;
  if constexpr (TRI) {
    int tri = gy * (gy + 1) / 2;
    int perz = tri * SPLITK;
    z = wg / perz;
    int rem = wg - z * perz;
    int ks = rem / tri;
    tpi = rem - ks * tri;
    int tp = tpi;
    bx = 0;
    while (tp >= gy - bx) { tp -= gy - bx; ++bx; }
    by = bx + tp;
    kbase = ks * K;
    zc = z * SPLITK + ks;
  } else {
    by = wg % gy;
    int t2 = wg / gy;
    bx = t2 % gx;
    z = t2 / gx;
    zc = z;
  }

  const unsigned short* pA0 = Ahi + (size_t)z * sA + (size_t)bx * BM * ldA;
  const unsigned short* pB0 = Bhi + (size_t)z * sB + (size_t)by * BN * ldB;
  const unsigned short* pA1 = SPLIT ? Alo + (size_t)z * sA + (size_t)bx * BM * ldA : pA0;
  const unsigned short* pB1 = SPLIT ? Blo + (size_t)z * sB + (size_t)by * BN * ldB : pB0;

  int tid = threadIdx.x;
  int lane = tid & 63, wid = tid >> 6;
  int wr = wid / NWN, wc = wid % NWN;
  int lr = lane & 15, kh2 = lane >> 4;

  f32x4 acc[MI][NI] = {};

  for (int k0 = kbase; k0 < kbase + K; k0 += BK) {
    // stage: 8 rows x 64 elems per 1KB chunk; lane l -> row +(l>>3), phys slot l&7.
    // element for phys slot s at row r is logical slot s^(r&7) (read applies same XOR)
#pragma unroll
    for (int i = 0; i < TOT / WAVES; ++i) {
      int c = wid + i * WAVES;
      const unsigned short* srcb; int ldX, lofs, rb2;
      if (c < CA)            { srcb = pA0; ldX = ldA; lofs = c * 512;                  rb2 = c * 8; }
      else if (c < NS * CA)  { srcb = pA1; ldX = ldA; lofs = BM * BK + (c - CA) * 512; rb2 = (c - CA) * 8; }
      else if (c < NS * CA + CB) { int cc = c - NS * CA; srcb = pB0; ldX = ldB;
                                   lofs = NS * BM * BK + cc * 512;                     rb2 = cc * 8; }
      else                   { int cc = c - NS * CA - CB; srcb = pB1; ldX = ldB;
                               lofs = NS * BM * BK + BN * BK + cc * 512;               rb2 = cc * 8; }
      int row = rb2 + (lane >> 3);
      const unsigned short* src =
          srcb + (size_t)row * ldX + k0 + (((lane & 7) ^ (row & 7)) << 3);
      __builtin_amdgcn_global_load_lds(
          (const __attribute__((address_space(1))) void*)src,
          (__attribute__((address_space(3))) void*)(lds + lofs), 16, 0, 0);
    }
    __syncthreads();

#pragma unroll
    for (int kk = 0; kk < BK / 32; ++kk) {
      bf16x8 ah[MI], al[MI], bh[NI], bl[NI];
#pragma unroll
      for (int m = 0; m < MI; ++m) {
        int row = wr * WM + m * 16 + lr;
        int so = ((((kk << 2) | kh2) ^ (row & 7)) << 3);
        ah[m] = *reinterpret_cast<const bf16x8*>(&lds[row * BK + so]);
        if constexpr (SPLIT)
          al[m] = *reinterpret_cast<const bf16x8*>(&lds[BM * BK + row * BK + so]);
      }
#pragma unroll
      for (int n = 0; n < NI; ++n) {
        int row = wc * WN + n * 16 + lr;
        int so = ((((kk << 2) | kh2) ^ (row & 7)) << 3);
        bh[n] = *reinterpret_cast<const bf16x8*>(&lds[NS * BM * BK + row * BK + so]);
        if constexpr (SPLIT)
          bl[n] = *reinterpret_cast<const bf16x8*>(&lds[NS * BM * BK + BN * BK + row * BK + so]);
      }
#pragma unroll
      for (int m = 0; m < MI; ++m)
#pragma unroll
        for (int n = 0; n < NI; ++n) {
          acc[m][n] = __builtin_amdgcn_mfma_f32_16x16x32_bf16(ah[m], bh[n], acc[m][n], 0, 0, 0);
          if constexpr (SPLIT) {
            acc[m][n] = __builtin_amdgcn_mfma_f32_16x16x32_bf16(ah[m], bl[n], acc[m][n], 0, 0, 0);
            acc[m][n] = __builtin_amdgcn_mfma_f32_16x16x32_bf16(al[m], bh[n], acc[m][n], 0, 0, 0);
          }
        }
    }
    __syncthreads();
  }

  // epilogue: C/D layout col = lane&15, row = (lane>>4)*4 + reg
  int lg = lane >> 4;
#pragma unroll
  for (int m = 0; m < MI; ++m)
#pragma unroll
    for (int n = 0; n < NI; ++n) {
      int lcol = wc * WN + n * 16 + lr;
      float bcol = (EPI == EPI_V) ? bias[by * BN + lcol] : 0.f;
#pragma unroll
      for (int r4 = 0; r4 < 4; ++r4) {
        int lrow = wr * WM + m * 16 + lg * 4 + r4;
        float v = acc[m][n][r4];
        if constexpr (COMPACT) {
          size_t idx = (size_t)zc * sC + (size_t)tpi * (BM * BN) + (size_t)lrow * BN + lcol;
          Cf[idx] = v;
        } else {
          size_t idx = (size_t)zc * sC + (size_t)(bx * BM + lrow) * ldC + (by * BN + lcol);
          if constexpr (EPI == EPI_F32) {
            Cf[idx] = v;
          } else if constexpr (EPI == EPI_HILO) {
            unsigned short h = f2bf(v);
            Chi[idx] = h;
            Clo[idx] = f2bf(v - bf2f(h));
          } else {
            Chi[idx] = f2bf(v + bcol);
          }
        }
      }
    }
}

// ---- reduce Gram split-K partials + hi/lo split; upper 128-blocks only ----
template <int KS>
__global__ void gram_reduce(const float* __restrict__ Gp,
                            unsigned short* __restrict__ Ghi, unsigned short* __restrict__ Glo) {
  int z = blockIdx.y;
  int tp = blockIdx.x;  // 0..14
  int b2 = tp, bx = 0;
  while (b2 >= 5 - bx) { b2 -= 5 - bx; ++bx; }
  int by = bx + b2;
  int t = threadIdx.x;
  const float* base = Gp + ((size_t)z * KS * 15 + tp) * (128 * 128);
  size_t gb = (size_t)z * CAUG * CAUG;
#pragma unroll
  for (int it = 0; it < 16; ++it) {
    int lrow = it * 8 + (t >> 5);
    int lc = (t & 31) * 4;
    f32x4 s = *reinterpret_cast<const f32x4*>(base + (size_t)lrow * 128 + lc);
#pragma unroll
    for (int ks = 1; ks < KS; ++ks)
      s += *reinterpret_cast<const f32x4*>(base + (size_t)ks * 15 * 128 * 128 +
                                           (size_t)lrow * 128 + lc);
    u16x4 h, l;
#pragma unroll
    for (int i = 0; i < 4; ++i) {
      unsigned short hh = f2bf(s[i]);
      h[i] = hh; l[i] = f2bf(s[i] - bf2f(hh));
    }
    size_t o = gb + (size_t)(bx * 128 + lrow) * CAUG + by * 128 + lc;
    *reinterpret_cast<u16x4*>(Ghi + o) = h;
    *reinterpret_cast<u16x4*>(Glo + o) = l;
  }
}

// ---- mirror lower triangle of G~ from computed upper (128-block pairs bx<by) ----
__global__ void mirror_g(unsigned short* __restrict__ Ghi, unsigned short* __restrict__ Glo) {
  __shared__ unsigned short shh[64][72], shl[64][72];
  int z = blockIdx.y;
  int pidx = blockIdx.x >> 2, sub = blockIdx.x & 3;
  int bx = 0, tp = pidx;
  while (tp >= 4 - bx) { tp -= 4 - bx; ++bx; }
  int by = bx + 1 + tp;
  int ti = bx * 2 + (sub & 1), tj = by * 2 + (sub >> 1);
  int t = threadIdx.x;
  int rr = t >> 2, cg = (t & 3) * 16;
  size_t gbase = (size_t)z * CAUG * CAUG;
  size_t so = gbase + (size_t)(ti * 64 + rr) * CAUG + tj * 64 + cg;
  *reinterpret_cast<u16x8*>(&shh[rr][cg]) = *reinterpret_cast<const u16x8*>(Ghi + so);
  *reinterpret_cast<u16x8*>(&shh[rr][cg + 8]) = *reinterpret_cast<const u16x8*>(Ghi + so + 8);
  *reinterpret_cast<u16x8*>(&shl[rr][cg]) = *reinterpret_cast<const u16x8*>(Glo + so);
  *reinterpret_cast<u16x8*>(&shl[rr][cg + 8]) = *reinterpret_cast<const u16x8*>(Glo + so + 8);
  __syncthreads();
  u16x8 oh, ol;
  size_t dst = gbase + (size_t)(tj * 64 + rr) * CAUG + ti * 64 + cg;
#pragma unroll
  for (int half = 0; half < 2; ++half) {
#pragma unroll
    for (int i = 0; i < 8; ++i) {
      oh[i] = shh[cg + half * 8 + i][rr];
      ol[i] = shl[cg + half * 8 + i][rr];
    }
    *reinterpret_cast<u16x8*>(Ghi + dst + half * 8) = oh;
    *reinterpret_cast<u16x8*>(Glo + dst + half * 8) = ol;
  }
}

// ---- row softmax: E fp32 [rows][512] -> attn bf16; one wave per row ----
__global__ void softmax_rows(const float* __restrict__ E, unsigned short* __restrict__ attn) {
  int lane = threadIdx.x & 63, wid = threadIdx.x >> 6;
  size_t row = (size_t)blockIdx.x * 4 + wid;
  const float* e = E + row * CD;
  const float4* ep = reinterpret_cast<const float4*>(e + lane * 8);
  float4 a = ep[0], bq4 = ep[1];
  float v[8] = {a.x, a.y, a.z, a.w, bq4.x, bq4.y, bq4.z, bq4.w};
  float m = v[0];
#pragma unroll
  for (int i = 1; i < 8; ++i) m = fmaxf(m, v[i]);
  for (int o = 32; o > 0; o >>= 1) m = fmaxf(m, __shfl_xor(m, o));
  float s = 0.f;
#pragma unroll
  for (int i = 0; i < 8; ++i) { v[i] = __expf(v[i] - m); s += v[i]; }
  for (int o = 32; o > 0; o >>= 1) s += __shfl_xor(s, o);
  float rinv = 1.0f / s;
  u16x4 h0, h1;
#pragma unroll
  for (int i = 0; i < 4; ++i) { h0[i] = f2bf(v[i] * rinv); h1[i] = f2bf(v[4 + i] * rinv); }
  unsigned short* op = attn + row * CD + lane * 8;
  *reinterpret_cast<u16x4*>(op) = h0;
  *reinterpret_cast<u16x4*>(op + 4) = h1;
}

extern "C" void kernel_launch(void* const* d_in, const int* in_sizes, int n_in,
                              void* d_out, int out_size, void* d_ws, size_t ws_size,
                              hipStream_t stream) {
  (void)in_sizes; (void)n_in; (void)out_size;
  const float* x  = (const float*)d_in[0];
  const float* Wq = (const float*)d_in[1];
  const float* bq = (const float*)d_in[2];
  const float* Wk = (const float*)d_in[3];
  const float* bk = (const float*)d_in[4];
  const float* Wv = (const float*)d_in[5];
  const float* bv = (const float*)d_in[6];
  float* out = (float*)d_out;

  char* base = (char*)d_ws;
  size_t off = 0;
  auto carve = [&](size_t bytes) -> char* {
    char* p = base + off;
    off += (bytes + 255) & ~(size_t)255;
    return p;
  };
  unsigned short* Wqh = (unsigned short*)carve((size_t)CD * KW * 2);
  unsigned short* Wql = (unsigned short*)carve((size_t)CD * KW * 2);
  unsigned short* Wkh = (unsigned short*)carve((size_t)CD * KW * 2);
  unsigned short* Wkl = (unsigned short*)carve((size_t)CD * KW * 2);
  unsigned short* Wvh = (unsigned short*)carve((size_t)CD * CD * 2);

  const size_t CP = (size_t)CD * PD;
  const size_t XS = (size_t)CAUG * PD;
  const size_t XT = (size_t)PD * CD;
  const size_t GG = (size_t)CAUG * CAUG;
  const size_t TT = (size_t)CD * CAUG;
  const size_t EE = (size_t)CD * CD;
  const size_t per_batch = 2 * XS * 2 + XT * 2 + 2 * GG * 2 + 2 * TT * 2 + EE * 4 + EE * 2 + XT * 2 + 2048;
  size_t rem = (ws_size > off + 4096) ? (ws_size - off - 4096) : 0;
  int nb = (int)(rem / per_batch);
  if (nb < 1) nb = 1;
  if (nb > BD) nb = BD;

  unsigned short* xsh = (unsigned short*)carve((size_t)nb * XS * 2);
  unsigned short* xsl = (unsigned short*)carve((size_t)nb * XS * 2);
  unsigned short* xth = (unsigned short*)carve((size_t)nb * XT * 2);
  unsigned short* Ghi = (unsigned short*)carve((size_t)nb * GG * 2);
  unsigned short* Glo = (unsigned short*)carve((size_t)nb * GG * 2);
  unsigned short* Thi = (unsigned short*)carve((size_t)nb * TT * 2);
  unsigned short* Tlo = (unsigned short*)carve((size_t)nb * TT * 2);
  float*          E   = (float*)carve((size_t)nb * EE * 4);
  unsigned short* att = (unsigned short*)carve((size_t)nb * EE * 2);
  unsigned short* vT  = (unsigned short*)carve((size_t)nb * XT * 2);

  // Gram split-K partials alias the E/att/vT region (all written after gram_reduce):
  // need nb*GKS*15*128*128*4 = nb*3.93MB <= nb*(EE*4 + EE*2 + XT*2) = nb*5.76MB
  float* Gpart = E;

  convert_w2<<<dim3((CD * KW + 255) / 256), 256, 0, stream>>>(
      Wq, bq, Wk, bk, Wv, Wqh, Wql, Wkh, Wkl, Wvh);

  for (int b0 = 0; b0 < BD; b0 += nb) {
    int cb = (BD - b0 < nb) ? (BD - b0) : nb;

    convert_x<<<dim3(PD / 64, 10, cb), 256, 0, stream>>>(x + (size_t)b0 * CP, xsh, xsl, xth);

    // G~ partials = Xa Xa^T (upper triangle blocks, split-K), fp32 compact out
    gemm2<128, 128, 64, 32, true, EPI_F32, true, GKS><<<15 * GKS * cb, 512, 0, stream>>>(
        xsh, xsl, xsh, xsl, (long long)XS, (long long)XS, PD, PD, PD / GKS,
        Gpart, nullptr, nullptr, (long long)15 * 128 * 128, 128, nullptr, 5, 5);

    gram_reduce<GKS><<<dim3(15, cb), 256, 0, stream>>>(Gpart, Ghi, Glo);

    mirror_g<<<dim3(40, cb), 256, 0, stream>>>(Ghi, Glo);

    // T = Wq~ * G~^T  (G symmetric), split, hi/lo out  [512][640]
    gemm2<64, 64, 32, 32, true, EPI_HILO, false><<<8 * 10 * cb, 256, 0, stream>>>(
        Wqh, Wql, Ghi, Glo, 0, (long long)GG, KW, CAUG, KW,
        nullptr, Thi, Tlo, (long long)TT, CAUG, nullptr, 8, 10);

    // E = T * Wk~^T, split, fp32 out [512][512]
    gemm2<64, 64, 32, 32, true, EPI_F32, false><<<8 * 8 * cb, 256, 0, stream>>>(
        Thi, Tlo, Wkh, Wkl, (long long)TT, 0, CAUG, KW, KW,
        E, nullptr, nullptr, (long long)EE, CD, nullptr, 8, 8);

    softmax_rows<<<dim3(cb * CD / 4), 256, 0, stream>>>(E, att);

    // vT[p][o] = xT * Wv^T + bv  [4096][512]
    gemm2<128, 128, 64, 64, false, EPI_V, false><<<32 * 4 * cb, 256, 0, stream>>>(
        xth, nullptr, Wvh, nullptr, (long long)XT, 0, CD, CD, CD,
        nullptr, vT, nullptr, (long long)XT, CD, bv, 32, 4);

    // out = attn * vT^T  [512][4096] fp32
    gemm2<128, 128, 64, 64, false, EPI_F32, false><<<4 * 32 * cb, 256, 0, stream>>>(
        att, nullptr, vT, nullptr, (long long)EE, (long long)XT, CD, CD, CD,
        out + (size_t)b0 * CP, nullptr, nullptr, (long long)CP, PD, nullptr, 4, 32);
  }
}